// Round 13
// baseline (619.133 us; speedup 1.0000x reference)
//
#include <hip/hip_runtime.h>
#include <hip/hip_fp16.h>

#define N_NODES  50000
#define E_EDGES  800000
#define E_TOT    850000   // E + N self-loops
#define H_HEADS  2
#define C_DIM    64
#define HC       128
#define L_LAYERS 3
#define OUT_DIM  128
#define G_GRAPHS 512
#define NEG_SLOPE 0.2f
#define NB       196      // node buckets of 256 nodes
#define EPB      4096     // edges per partition block
#define NCHUNK   208      // ceil(E_TOT/EPB)
#define RMAX     80       // slots per (bucket,chunk) run; Binom mean 20.9, sigma 4.6 -> ~13-sigma
#define BSTRIDE  4864     // fixed src_sorted slots per bucket (mean 4352, sigma 64 -> 8-sigma)

typedef float v2f __attribute__((ext_vector_type(2)));

__device__ __forceinline__ void lds_fence() { asm volatile("" ::: "memory"); }

// ---- prelude (single dispatch, 3 independent jobs by block range):
// blocks [0,NCHUNK): atomic-free edge partition into fixed (bucket,chunk) runs
//                    + grid-stride zero of the graph-output accumulator.
// blocks [NCHUNK,..): layer-0 fused linears (embed gather + h2 + xl/xr fp16).
// No inter-job dependency -> no sync needed; partition hides under lin0. ----
__global__ void __launch_bounds__(256)
prelude_kernel(const int* __restrict__ srcs, const int* __restrict__ dsts,
               float* __restrict__ out,
               int* __restrict__ rcnt, unsigned int* __restrict__ ebuf,
               const int* __restrict__ xs, const float* __restrict__ etab,
               const float* __restrict__ W, const float* __restrict__ b,
               const float* __restrict__ Wl, const float* __restrict__ bl,
               const float* __restrict__ Wr, const float* __restrict__ br,
               __half* __restrict__ xlh, __half* __restrict__ xrh) {
    __shared__ __align__(16) char smem[20480];   // partition: 4KB ctrl + 16KB sval; lin: 8KB
    int tid = threadIdx.x;
    int bid = blockIdx.x;

    if (bid < NCHUNK) {
        // ---------- edge partition (atomic-free, fixed-run layout) ----------
        int* hist  = (int*)smem;
        int* lscan = hist + 256;
        int* sExcl = lscan + 256;
        int* lcnt  = sExcl + 256;
        unsigned int* sval = (unsigned int*)(lcnt + 256);

        // zero graph-output accumulator (consumed by readout, 7 dispatches later)
        for (int i = bid * 256 + tid; i < G_GRAPHS * OUT_DIM; i += NCHUNK * 256)
            out[i] = 0.f;

        int ebase = bid * EPB;
        hist[tid] = 0;
        __syncthreads();
        unsigned int val[16];
        int gid[16];
#pragma unroll
        for (int i = 0; i < 16; i++) {
            int e = ebase + i * 256 + tid;
            if (e < E_TOT) {
                int s, d;
                if (e < E_EDGES) { s = srcs[e]; d = dsts[e]; }
                else             { s = d = e - E_EDGES; }
                val[i] = ((unsigned)s << 16) | (unsigned)d;   // both < 2^16
                gid[i] = d >> 8;
                atomicAdd(&hist[gid[i]], 1);
            } else gid[i] = -1;
        }
        __syncthreads();
        lscan[tid] = hist[tid];
        __syncthreads();
#pragma unroll
        for (int off = 1; off < 256; off <<= 1) {
            int t = (tid >= off) ? lscan[tid - off] : 0;
            __syncthreads();
            lscan[tid] += t;
            __syncthreads();
        }
        sExcl[tid] = lscan[tid] - hist[tid];
        lcnt[tid] = 0;
        __syncthreads();
#pragma unroll
        for (int i = 0; i < 16; i++) {
            if (gid[i] >= 0) {
                int off = atomicAdd(&lcnt[gid[i]], 1);
                sval[sExcl[gid[i]] + off] = val[i];
            }
        }
        if (tid < NB) rcnt[bid * NB + tid] = hist[tid];
        __syncthreads();
        int total = lscan[255];
        for (int idx = tid; idx < total; idx += 256) {
            unsigned int v = sval[idx];
            int g = (int)((v & 0xFFFFu) >> 8);
            ebuf[((size_t)g * NCHUNK + bid) * RMAX + (idx - sExcl[g])] = v;
        }
    } else {
        // ---------- layer-0 fused linears (embed gather) ----------
        float* sH  = (float*)smem;
        float* sH2 = sH + 16 * 64;
        int base = (bid - NCHUNK) * 16;
#pragma unroll
        for (int i = 0; i < 4; i++) {
            int idx = tid + i * 256;
            int nn = base + (idx >> 6);
            int cc = idx & 63;
            float hv = 0.f;
            if (nn < N_NODES) hv = etab[xs[nn] * 64 + cc];
            sH[idx] = hv;
        }
        __syncthreads();
        {
            int c = tid & 63, g = tid >> 6;
            v2f a2[4];
#pragma unroll
            for (int n = 0; n < 4; n++) a2[n] = (v2f){b[c], 0.f};
            for (int k = 0; k < 64; k += 2) {
                v2f w2 = {W[k * 64 + c], W[(k + 1) * 64 + c]};
#pragma unroll
                for (int n = 0; n < 4; n++) {
                    v2f hv2 = *(const v2f*)&sH[(g * 4 + n) * 64 + k];
                    a2[n] = __builtin_elementwise_fma(hv2, w2, a2[n]);
                }
            }
#pragma unroll
            for (int n = 0; n < 4; n++)
                sH2[(g * 4 + n) * 64 + c] = fmaxf(a2[n].x + a2[n].y, 0.f);
        }
        __syncthreads();
        {
            int j = tid & 127, gg = tid >> 7;
            v2f accl2[8], accr2[8];
#pragma unroll
            for (int n = 0; n < 8; n++) {
                accl2[n] = (v2f){bl[j], 0.f};
                accr2[n] = (v2f){br[j], 0.f};
            }
            for (int k = 0; k < 64; k += 2) {
                v2f wl2 = {Wl[k * 128 + j], Wl[(k + 1) * 128 + j]};
                v2f wr2 = {Wr[k * 128 + j], Wr[(k + 1) * 128 + j]};
#pragma unroll
                for (int n = 0; n < 8; n++) {
                    v2f hv2 = *(const v2f*)&sH2[(gg * 8 + n) * 64 + k];
                    accl2[n] = __builtin_elementwise_fma(hv2, wl2, accl2[n]);
                    accr2[n] = __builtin_elementwise_fma(hv2, wr2, accr2[n]);
                }
            }
            int hh = j >> 6, c = j & 63;
#pragma unroll
            for (int n = 0; n < 8; n++) {
                int node = base + gg * 8 + n;
                if (node < N_NODES) {
                    size_t o = (size_t)node * 128 + c * 2 + hh;
                    xlh[o] = __float2half(accl2[n].x + accl2[n].y);
                    xrh[o] = __float2half(accr2[n].x + accr2[n].y);
                }
            }
        }
    }
}

// ---- per-bucket: gather this bucket's 208 runs, node histogram -> row_se
// (start,end), then in-window scatter (ushort src). uint4 run loads. ----
__global__ void bucket_csr_kernel(const unsigned int* __restrict__ ebuf,
                                  const int* __restrict__ rcnt,
                                  int2* __restrict__ row_se,
                                  unsigned short* __restrict__ src_sorted) {
    __shared__ int hist[256];
    __shared__ int lcnt[256];
    __shared__ int wsum[4];
    int g = blockIdx.x, tid = threadIdx.x;
    int n0 = g << 8;
    int nodes = min(256, N_NODES - n0);
    hist[tid] = 0;
    lcnt[tid] = 0;
    __syncthreads();
    // pass A: histogram over all runs of this bucket
    for (int blk = tid; blk < NCHUNK; blk += 256) {
        int c = rcnt[blk * NB + g];
        const uint4* rp = (const uint4*)&ebuf[((size_t)g * NCHUNK + blk) * RMAX];
        for (int i = 0; i < c; i += 4) {
            uint4 v4 = rp[i >> 2];
            if (i + 0 < c) atomicAdd(&hist[v4.x & 255], 1);
            if (i + 1 < c) atomicAdd(&hist[v4.y & 255], 1);
            if (i + 2 < c) atomicAdd(&hist[v4.z & 255], 1);
            if (i + 3 < c) atomicAdd(&hist[v4.w & 255], 1);
        }
    }
    __syncthreads();
    int c = hist[tid];
    int v = c;
    int lane = tid & 63, wid = tid >> 6;
#pragma unroll
    for (int off = 1; off < 64; off <<= 1) {
        int t = __shfl_up(v, off, 64);
        if (lane >= off) v += t;
    }
    if (lane == 63) wsum[wid] = v;
    __syncthreads();
    int woff = 0;
#pragma unroll
    for (int w = 0; w < 4; w++) if (w < wid) woff += wsum[w];
    v += woff;
    int nbase = g * BSTRIDE + v - c;     // slot base for node n0+tid
    if (tid < nodes) row_se[n0 + tid] = make_int2(nbase, nbase + c);
    __syncthreads();
    hist[tid] = nbase;                   // reuse hist as per-node base
    __syncthreads();
    // pass B: scatter within the bucket's contiguous window
    for (int blk = tid; blk < NCHUNK; blk += 256) {
        int c2 = rcnt[blk * NB + g];
        const uint4* rp = (const uint4*)&ebuf[((size_t)g * NCHUNK + blk) * RMAX];
        for (int i = 0; i < c2; i += 4) {
            uint4 v4 = rp[i >> 2];
            unsigned int vv0 = v4.x, vv1 = v4.y, vv2 = v4.z, vv3 = v4.w;
            if (i + 0 < c2) { int dl = vv0 & 255; int slot = hist[dl] + atomicAdd(&lcnt[dl], 1); src_sorted[slot] = (unsigned short)(vv0 >> 16); }
            if (i + 1 < c2) { int dl = vv1 & 255; int slot = hist[dl] + atomicAdd(&lcnt[dl], 1); src_sorted[slot] = (unsigned short)(vv1 >> 16); }
            if (i + 2 < c2) { int dl = vv2 & 255; int slot = hist[dl] + atomicAdd(&lcnt[dl], 1); src_sorted[slot] = (unsigned short)(vv2 >> 16); }
            if (i + 3 < c2) { int dl = vv3 & 255; int slot = hist[dl] + atomicAdd(&lcnt[dl], 1); src_sorted[slot] = (unsigned short)(vv3 >> 16); }
        }
    }
}

// ---- layers 1..2 fused linears (no embed gather), k-paired pk_fma ----
__global__ void layer_lin_kernel(const float* __restrict__ h,
                                 const float* __restrict__ W, const float* __restrict__ b,
                                 const float* __restrict__ Wl, const float* __restrict__ bl,
                                 const float* __restrict__ Wr, const float* __restrict__ br,
                                 __half* __restrict__ xlh, __half* __restrict__ xrh) {
    __shared__ float sH[16 * 64];
    __shared__ float sH2[16 * 64];
    int tid = threadIdx.x;
    int base = blockIdx.x * 16;
#pragma unroll
    for (int i = 0; i < 4; i++) {
        int idx = tid + i * 256;
        int nn = base + (idx >> 6);
        int cc = idx & 63;
        sH[idx] = (nn < N_NODES) ? h[(size_t)nn * 64 + cc] : 0.f;
    }
    __syncthreads();
    {
        int c = tid & 63, g = tid >> 6;
        v2f a2[4];
#pragma unroll
        for (int n = 0; n < 4; n++) a2[n] = (v2f){b[c], 0.f};
        for (int k = 0; k < 64; k += 2) {
            v2f w2 = {W[k * 64 + c], W[(k + 1) * 64 + c]};
#pragma unroll
            for (int n = 0; n < 4; n++) {
                v2f hv2 = *(const v2f*)&sH[(g * 4 + n) * 64 + k];
                a2[n] = __builtin_elementwise_fma(hv2, w2, a2[n]);
            }
        }
#pragma unroll
        for (int n = 0; n < 4; n++)
            sH2[(g * 4 + n) * 64 + c] = fmaxf(a2[n].x + a2[n].y, 0.f);
    }
    __syncthreads();
    {
        int j = tid & 127, gg = tid >> 7;
        v2f accl2[8], accr2[8];
#pragma unroll
        for (int n = 0; n < 8; n++) {
            accl2[n] = (v2f){bl[j], 0.f};
            accr2[n] = (v2f){br[j], 0.f};
        }
        for (int k = 0; k < 64; k += 2) {
            v2f wl2 = {Wl[k * 128 + j], Wl[(k + 1) * 128 + j]};
            v2f wr2 = {Wr[k * 128 + j], Wr[(k + 1) * 128 + j]};
#pragma unroll
            for (int n = 0; n < 8; n++) {
                v2f hv2 = *(const v2f*)&sH2[(gg * 8 + n) * 64 + k];
                accl2[n] = __builtin_elementwise_fma(hv2, wl2, accl2[n]);
                accr2[n] = __builtin_elementwise_fma(hv2, wr2, accr2[n]);
            }
        }
        int hh = j >> 6, c = j & 63;
#pragma unroll
        for (int n = 0; n < 8; n++) {
            int node = base + gg * 8 + n;
            if (node < N_NODES) {
                size_t o = (size_t)node * 128 + c * 2 + hh;
                xlh[o] = __float2half(accl2[n].x + accl2[n].y);
                xrh[o] = __float2half(accr2[n].x + accr2[n].y);
            }
        }
    }
}

// ---- GATv2 edge phase (proven, 2-wave blocks): one wave per dst node,
// lane = channel, half2 = both heads. 8-edge batches, register-held fp16 vl,
// ping-pong prefetch, LDS-transpose score reduction, packed fp32 math,
// no running max, readlane weight broadcast. row_se int2 (start,end). ----
__global__ void __launch_bounds__(128)
gat_kernel(const __half2* __restrict__ xlh, const __half2* __restrict__ xrh2,
           const float* __restrict__ att, const int2* __restrict__ row_se,
           const unsigned short* __restrict__ src_sorted,
           const float* __restrict__ bias,
           float* __restrict__ h_out) {
    __shared__ __align__(16) float cbuf[2][8 * 132];
    int w = threadIdx.x >> 6;
    int d = blockIdx.x * 2 + w;
    if (d >= N_NODES) return;
    int lane = threadIdx.x & 63;
    int2 se = row_se[d];
    int r0 = se.x, r1 = se.y;
    float2 vrf = __half22float2(xrh2[(size_t)d * 64 + lane]);
    v2f vr2 = {vrf.x, vrf.y};
    v2f att2 = {att[lane], att[64 + lane]};
    float* cb = cbuf[w];
    int e_of = lane >> 3, p = lane & 7;

    float dpx = 0.f, dpy = 0.f;
    v2f ac0 = {0.f, 0.f}, ac1 = {0.f, 0.f};

#define GAT_LOAD(V, CB) do {                                                    \
        int lim_ = nchunk - 1;                                                  \
        _Pragma("unroll")                                                       \
        for (int e = 0; e < 8; e++) {                                           \
            int ee_ = (CB) + e;                                                 \
            int sv_ = __builtin_amdgcn_readlane(idx, (ee_ < nchunk) ? ee_ : lim_); \
            V[e] = xlh[(size_t)sv_ * 64 + lane];                                \
        }                                                                       \
    } while (0)

#define GAT_PROC(V, CB) do {                                                    \
        int rem_ = nchunk - (CB);                                               \
        v2f vf8[8];                                                             \
        _Pragma("unroll")                                                       \
        for (int e = 0; e < 8; e++) {                                           \
            float2 vf_ = __half22float2(V[e]);                                  \
            v2f vl2 = {vf_.x, vf_.y};                                           \
            vf8[e] = vl2;                                                       \
            v2f z = vl2 + vr2;                                                  \
            v2f t = __builtin_elementwise_max(z, z * NEG_SLOPE) * att2;         \
            *(v2f*)&cb[e * 132 + 2 * lane] = t;                                 \
        }                                                                       \
        lds_fence();                                                            \
        v2f s2 = {0.f, 0.f};                                                    \
        {                                                                       \
            const float4* row_ = (const float4*)&cb[e_of * 132 + p * 16];       \
            _Pragma("unroll")                                                   \
            for (int j = 0; j < 4; j++) {                                       \
                float4 f = row_[j];                                             \
                s2 += (v2f){f.x, f.y};                                          \
                s2 += (v2f){f.z, f.w};                                          \
            }                                                                   \
        }                                                                       \
        lds_fence();                                                            \
        _Pragma("unroll")                                                       \
        for (int off = 1; off <= 4; off <<= 1) {                                \
            v2f o_;                                                             \
            o_.x = __shfl_xor(s2.x, off, 64);                                   \
            o_.y = __shfl_xor(s2.y, off, 64);                                   \
            s2 += o_;                                                           \
        }                                                                       \
        float sx = s2.x, sy = s2.y;                                             \
        if (e_of >= rem_) { sx = -INFINITY; sy = -INFINITY; }                   \
        float wx = __expf(sx), wy = __expf(sy);                                 \
        dpx += wx; dpy += wy;                                                   \
        _Pragma("unroll")                                                       \
        for (int e = 0; e < 8; e++) {                                           \
            float swx = __int_as_float(__builtin_amdgcn_readlane(__float_as_int(wx), 8 * e)); \
            float swy = __int_as_float(__builtin_amdgcn_readlane(__float_as_int(wy), 8 * e)); \
            v2f w2 = {swx, swy};                                                \
            if (e & 1) ac1 = __builtin_elementwise_fma(w2, vf8[e], ac1);        \
            else       ac0 = __builtin_elementwise_fma(w2, vf8[e], ac0);        \
        }                                                                       \
    } while (0)

    for (int base = r0; base < r1; base += 64) {
        int a = base + lane;
        int idx = (int)src_sorted[(a < r1) ? a : (r1 - 1)];
        int nchunk = min(64, r1 - base);
        __half2 va[8], vb[8];
        GAT_LOAD(va, 0);
        int cb_i = 0;
        for (;;) {
            int nx = cb_i + 8;
            if (nx < nchunk) {
                GAT_LOAD(vb, nx);
                GAT_PROC(va, cb_i);
                cb_i = nx;
            } else {
                GAT_PROC(va, cb_i);
                break;
            }
            nx = cb_i + 8;
            if (nx < nchunk) {
                GAT_LOAD(va, nx);
                GAT_PROC(vb, cb_i);
                cb_i = nx;
            } else {
                GAT_PROC(vb, cb_i);
                break;
            }
        }
    }
#undef GAT_LOAD
#undef GAT_PROC

#pragma unroll
    for (int off = 8; off <= 32; off <<= 1) {
        dpx += __shfl_xor(dpx, off, 64);
        dpy += __shfl_xor(dpy, off, 64);
    }
    v2f acc = ac0 + ac1;
    h_out[(size_t)d * 64 + lane] = (acc.x / dpx + acc.y / dpy) * 0.5f + bias[lane];
}

// ---- readout GEMM fused with per-graph segment sum (proven version) ----
__global__ void readout_kernel(const float* __restrict__ h, const float* __restrict__ W,
                               const float* __restrict__ b, const int* __restrict__ batch,
                               float* __restrict__ out) {
    __shared__ float sH[16 * 64];
    __shared__ int sB[16];
    int tid = threadIdx.x;
    int base = blockIdx.x * 16;
#pragma unroll
    for (int i = 0; i < 4; i++) {
        int idx = tid + i * 256;
        int nn = base + (idx >> 6);
        sH[idx] = (nn < N_NODES) ? h[(size_t)nn * 64 + (idx & 63)] : 0.f;
    }
    if (tid < 16) sB[tid] = (base + tid < N_NODES) ? batch[base + tid] : -1;
    __syncthreads();
    int j = tid & 127, gg = tid >> 7;
    float acc[8];
#pragma unroll
    for (int n = 0; n < 8; n++) acc[n] = b[j];
    for (int k = 0; k < 64; k++) {
        float wv = W[k * OUT_DIM + j];
#pragma unroll
        for (int n = 0; n < 8; n++) acc[n] = fmaf(sH[(gg * 8 + n) * 64 + k], wv, acc[n]);
    }
    float run = 0.f; int curb = -2;
#pragma unroll
    for (int n = 0; n < 8; n++) {
        int node = base + gg * 8 + n;
        int bb = (node < N_NODES) ? sB[gg * 8 + n] : -1;
        if (bb != curb) {
            if (curb >= 0) atomicAdd(&out[curb * OUT_DIM + j], run);
            run = 0.f; curb = bb;
        }
        if (bb >= 0) run += acc[n];
    }
    if (curb >= 0) atomicAdd(&out[curb * OUT_DIM + j], run);
}

extern "C" void kernel_launch(void* const* d_in, const int* in_sizes, int n_in,
                              void* d_out, int out_size, void* d_ws, size_t ws_size,
                              hipStream_t stream) {
    const int*   x        = (const int*)d_in[0];
    const int*   edge     = (const int*)d_in[1];
    const int*   batch    = (const int*)d_in[2];
    const float* embed    = (const float*)d_in[4];
    const float* lin_W    = (const float*)d_in[5];
    const float* lin_b    = (const float*)d_in[6];
    const float* gat_Wl   = (const float*)d_in[7];
    const float* gat_bl   = (const float*)d_in[8];
    const float* gat_Wr   = (const float*)d_in[9];
    const float* gat_br   = (const float*)d_in[10];
    const float* gat_att  = (const float*)d_in[11];
    const float* gat_bias = (const float*)d_in[12];
    const float* ro_W     = (const float*)d_in[13];
    const float* ro_b     = (const float*)d_in[14];
    float* out = (float*)d_out;

    const int* srcs = edge;
    const int* dsts = edge + E_EDGES;

    float* h    = (float*)d_ws;
    __half* xlh = (__half*)(h + (size_t)N_NODES * 64);
    __half* xrh = xlh + (size_t)N_NODES * HC;
    int2* row_se       = (int2*)(xrh + (size_t)N_NODES * HC);
    int* rcnt          = (int*)(row_se + N_NODES);                      // NCHUNK*NB
    unsigned int* ebuf = (unsigned int*)(rcnt + NCHUNK * NB);           // NB*NCHUNK*RMAX (+slack)
    unsigned short* src_sorted =
        (unsigned short*)(ebuf + (size_t)NB * NCHUNK * RMAX + 4096);    // NB*BSTRIDE

    const int T = 256;
    const int gLin = (N_NODES + 15) / 16;
    const int gGat = (N_NODES + 1) / 2;

    // D1: edge partition (+out zero) || layer-0 linears, one dispatch
    prelude_kernel<<<NCHUNK + gLin, T, 0, stream>>>(
        srcs, dsts, out, rcnt, ebuf, x, embed,
        lin_W, lin_b, gat_Wl, gat_bl, gat_Wr, gat_br, xlh, xrh);
    // D2: per-bucket CSR + scatter
    bucket_csr_kernel<<<NB, T, 0, stream>>>(ebuf, rcnt, row_se, src_sorted);
    // D3..D7: gat0, (lin,gat) x2
    gat_kernel<<<gGat, 128, 0, stream>>>(
        (const __half2*)xlh, (const __half2*)xrh, gat_att,
        row_se, src_sorted, gat_bias, h);
    for (int l = 1; l < L_LAYERS; l++) {
        layer_lin_kernel<<<gLin, T, 0, stream>>>(
            h,
            lin_W + (size_t)l * 64 * 64, lin_b + (size_t)l * 64,
            gat_Wl + (size_t)l * 64 * 128, gat_bl + (size_t)l * 128,
            gat_Wr + (size_t)l * 64 * 128, gat_br + (size_t)l * 128,
            xlh, xrh);
        gat_kernel<<<gGat, 128, 0, stream>>>(
            (const __half2*)xlh, (const __half2*)xrh, gat_att + (size_t)l * HC,
            row_se, src_sorted, gat_bias + (size_t)l * 64, h);
    }
    // D8: readout + segment sum
    readout_kernel<<<gLin, T, 0, stream>>>(h, ro_W, ro_b, batch, out);
}

// Round 14
// 404.569 us; speedup vs baseline: 1.5304x; 1.5304x over previous
//
#include <hip/hip_runtime.h>
#include <hip/hip_fp16.h>

#define N_NODES  50000
#define E_EDGES  800000
#define E_TOT    850000   // E + N self-loops
#define H_HEADS  2
#define C_DIM    64
#define HC       128
#define L_LAYERS 3
#define OUT_DIM  128
#define G_GRAPHS 512
#define NEG_SLOPE 0.2f
#define NB       196      // node buckets of 256 nodes
#define EPB      4096     // edges per partition block
#define NCHUNK   208      // ceil(E_TOT/EPB)
#define RMAX     80       // slots per (bucket,chunk) run; Binom mean 20.9, sigma 4.6 -> ~13-sigma
#define BSTRIDE  4864     // fixed src_sorted slots per bucket (mean 4352, sigma 64 -> 8-sigma)

typedef float v2f __attribute__((ext_vector_type(2)));

__device__ __forceinline__ void lds_fence() { asm volatile("" ::: "memory"); }

// ---- standalone atomic-free edge partition (r13 logic, verified-correct;
// kept UNFUSED to avoid the r13 regalloc-union spill). Each block owns one
// 4096-edge chunk, reorders into per-bucket runs in LDS, writes fixed
// (bucket,chunk) runs + rcnt. Also grid-stride zeros the graph-output
// accumulator (folds the old init dispatch). ----
__global__ void __launch_bounds__(256)
edge_partition_kernel(const int* __restrict__ srcs, const int* __restrict__ dsts,
                      float* __restrict__ out,
                      int* __restrict__ rcnt, unsigned int* __restrict__ ebuf) {
    __shared__ int hist[256];
    __shared__ int lscan[256];
    __shared__ int sExcl[256];
    __shared__ int lcnt[256];
    __shared__ unsigned int sval[EPB];
    int tid = threadIdx.x;
    int bid = blockIdx.x;

    // zero graph-output accumulator (consumed by readout much later)
    for (int i = bid * 256 + tid; i < G_GRAPHS * OUT_DIM; i += NCHUNK * 256)
        out[i] = 0.f;

    int ebase = bid * EPB;
    hist[tid] = 0;
    __syncthreads();
    unsigned int val[16];
    int gid[16];
#pragma unroll
    for (int i = 0; i < 16; i++) {
        int e = ebase + i * 256 + tid;
        if (e < E_TOT) {
            int s, d;
            if (e < E_EDGES) { s = srcs[e]; d = dsts[e]; }
            else             { s = d = e - E_EDGES; }
            val[i] = ((unsigned)s << 16) | (unsigned)d;   // both < 2^16
            gid[i] = d >> 8;
            atomicAdd(&hist[gid[i]], 1);
        } else gid[i] = -1;
    }
    __syncthreads();
    lscan[tid] = hist[tid];
    __syncthreads();
#pragma unroll
    for (int off = 1; off < 256; off <<= 1) {
        int t = (tid >= off) ? lscan[tid - off] : 0;
        __syncthreads();
        lscan[tid] += t;
        __syncthreads();
    }
    sExcl[tid] = lscan[tid] - hist[tid];
    lcnt[tid] = 0;
    __syncthreads();
#pragma unroll
    for (int i = 0; i < 16; i++) {
        if (gid[i] >= 0) {
            int off = atomicAdd(&lcnt[gid[i]], 1);
            sval[sExcl[gid[i]] + off] = val[i];
        }
    }
    if (tid < NB) rcnt[bid * NB + tid] = hist[tid];
    __syncthreads();
    int total = lscan[255];
    for (int idx = tid; idx < total; idx += 256) {
        unsigned int v = sval[idx];
        int g = (int)((v & 0xFFFFu) >> 8);
        ebuf[((size_t)g * NCHUNK + bid) * RMAX + (idx - sExcl[g])] = v;
    }
}

// ---- per-bucket: gather this bucket's runs, node histogram -> row_se
// (start,end), then in-window scatter (ushort src). r13-verified logic. ----
__global__ void bucket_csr_kernel(const unsigned int* __restrict__ ebuf,
                                  const int* __restrict__ rcnt,
                                  int2* __restrict__ row_se,
                                  unsigned short* __restrict__ src_sorted) {
    __shared__ int hist[256];
    __shared__ int lcnt[256];
    __shared__ int wsum[4];
    int g = blockIdx.x, tid = threadIdx.x;
    int n0 = g << 8;
    int nodes = min(256, N_NODES - n0);
    hist[tid] = 0;
    lcnt[tid] = 0;
    __syncthreads();
    // pass A: histogram over all runs of this bucket
    for (int blk = tid; blk < NCHUNK; blk += 256) {
        int c = rcnt[blk * NB + g];
        const uint4* rp = (const uint4*)&ebuf[((size_t)g * NCHUNK + blk) * RMAX];
        for (int i = 0; i < c; i += 4) {
            uint4 v4 = rp[i >> 2];
            if (i + 0 < c) atomicAdd(&hist[v4.x & 255], 1);
            if (i + 1 < c) atomicAdd(&hist[v4.y & 255], 1);
            if (i + 2 < c) atomicAdd(&hist[v4.z & 255], 1);
            if (i + 3 < c) atomicAdd(&hist[v4.w & 255], 1);
        }
    }
    __syncthreads();
    int c = hist[tid];
    int v = c;
    int lane = tid & 63, wid = tid >> 6;
#pragma unroll
    for (int off = 1; off < 64; off <<= 1) {
        int t = __shfl_up(v, off, 64);
        if (lane >= off) v += t;
    }
    if (lane == 63) wsum[wid] = v;
    __syncthreads();
    int woff = 0;
#pragma unroll
    for (int w = 0; w < 4; w++) if (w < wid) woff += wsum[w];
    v += woff;
    int nbase = g * BSTRIDE + v - c;     // slot base for node n0+tid
    if (tid < nodes) row_se[n0 + tid] = make_int2(nbase, nbase + c);
    __syncthreads();
    hist[tid] = nbase;                   // reuse hist as per-node base
    __syncthreads();
    // pass B: scatter within the bucket's contiguous window
    for (int blk = tid; blk < NCHUNK; blk += 256) {
        int c2 = rcnt[blk * NB + g];
        const uint4* rp = (const uint4*)&ebuf[((size_t)g * NCHUNK + blk) * RMAX];
        for (int i = 0; i < c2; i += 4) {
            uint4 v4 = rp[i >> 2];
            unsigned int vv0 = v4.x, vv1 = v4.y, vv2 = v4.z, vv3 = v4.w;
            if (i + 0 < c2) { int dl = vv0 & 255; int slot = hist[dl] + atomicAdd(&lcnt[dl], 1); src_sorted[slot] = (unsigned short)(vv0 >> 16); }
            if (i + 1 < c2) { int dl = vv1 & 255; int slot = hist[dl] + atomicAdd(&lcnt[dl], 1); src_sorted[slot] = (unsigned short)(vv1 >> 16); }
            if (i + 2 < c2) { int dl = vv2 & 255; int slot = hist[dl] + atomicAdd(&lcnt[dl], 1); src_sorted[slot] = (unsigned short)(vv2 >> 16); }
            if (i + 3 < c2) { int dl = vv3 & 255; int slot = hist[dl] + atomicAdd(&lcnt[dl], 1); src_sorted[slot] = (unsigned short)(vv3 >> 16); }
        }
    }
}

// ---- fused per-layer linears (r12-proven): h2 = relu(in@W+b); xl = h2@Wl+bl
// (fp16); xr = h2@Wr+br (fp16). k-paired pk_fma; node-major LDS broadcasts.
// Layer 0 fuses the embedding gather. ----
__global__ void layer_lin_kernel(const float* __restrict__ h,
                                 const int* __restrict__ xs, const float* __restrict__ etab,
                                 int use_embed,
                                 const float* __restrict__ W, const float* __restrict__ b,
                                 const float* __restrict__ Wl, const float* __restrict__ bl,
                                 const float* __restrict__ Wr, const float* __restrict__ br,
                                 __half* __restrict__ xlh, __half* __restrict__ xrh) {
    __shared__ float sH[16 * 64];
    __shared__ float sH2[16 * 64];
    int tid = threadIdx.x;
    int base = blockIdx.x * 16;
#pragma unroll
    for (int i = 0; i < 4; i++) {
        int idx = tid + i * 256;
        int nn = base + (idx >> 6);
        int cc = idx & 63;
        float hv = 0.f;
        if (nn < N_NODES)
            hv = use_embed ? etab[xs[nn] * 64 + cc] : h[(size_t)nn * 64 + cc];
        sH[idx] = hv;
    }
    __syncthreads();
    {
        int c = tid & 63, g = tid >> 6;
        v2f a2[4];
#pragma unroll
        for (int n = 0; n < 4; n++) a2[n] = (v2f){b[c], 0.f};
        for (int k = 0; k < 64; k += 2) {
            v2f w2 = {W[k * 64 + c], W[(k + 1) * 64 + c]};
#pragma unroll
            for (int n = 0; n < 4; n++) {
                v2f hv2 = *(const v2f*)&sH[(g * 4 + n) * 64 + k];
                a2[n] = __builtin_elementwise_fma(hv2, w2, a2[n]);
            }
        }
#pragma unroll
        for (int n = 0; n < 4; n++)
            sH2[(g * 4 + n) * 64 + c] = fmaxf(a2[n].x + a2[n].y, 0.f);
    }
    __syncthreads();
    {
        int j = tid & 127, gg = tid >> 7;
        v2f accl2[8], accr2[8];
#pragma unroll
        for (int n = 0; n < 8; n++) {
            accl2[n] = (v2f){bl[j], 0.f};
            accr2[n] = (v2f){br[j], 0.f};
        }
        for (int k = 0; k < 64; k += 2) {
            v2f wl2 = {Wl[k * 128 + j], Wl[(k + 1) * 128 + j]};
            v2f wr2 = {Wr[k * 128 + j], Wr[(k + 1) * 128 + j]};
#pragma unroll
            for (int n = 0; n < 8; n++) {
                v2f hv2 = *(const v2f*)&sH2[(gg * 8 + n) * 64 + k];
                accl2[n] = __builtin_elementwise_fma(hv2, wl2, accl2[n]);
                accr2[n] = __builtin_elementwise_fma(hv2, wr2, accr2[n]);
            }
        }
        int hh = j >> 6, c = j & 63;
#pragma unroll
        for (int n = 0; n < 8; n++) {
            int node = base + gg * 8 + n;
            if (node < N_NODES) {
                size_t o = (size_t)node * 128 + c * 2 + hh;
                xlh[o] = __float2half(accl2[n].x + accl2[n].y);
                xrh[o] = __float2half(accr2[n].x + accr2[n].y);
            }
        }
    }
}

// ---- GATv2 edge phase (proven, 2-wave blocks): one wave per dst node,
// lane = channel, half2 = both heads. 8-edge batches, register-held fp16 vl,
// ping-pong prefetch, LDS-transpose score reduction, packed fp32 math,
// no running max, readlane weight broadcast. row_se int2 (start,end). ----
__global__ void __launch_bounds__(128)
gat_kernel(const __half2* __restrict__ xlh, const __half2* __restrict__ xrh2,
           const float* __restrict__ att, const int2* __restrict__ row_se,
           const unsigned short* __restrict__ src_sorted,
           const float* __restrict__ bias,
           float* __restrict__ h_out) {
    __shared__ __align__(16) float cbuf[2][8 * 132];
    int w = threadIdx.x >> 6;
    int d = blockIdx.x * 2 + w;
    if (d >= N_NODES) return;
    int lane = threadIdx.x & 63;
    int2 se = row_se[d];
    int r0 = se.x, r1 = se.y;
    float2 vrf = __half22float2(xrh2[(size_t)d * 64 + lane]);
    v2f vr2 = {vrf.x, vrf.y};
    v2f att2 = {att[lane], att[64 + lane]};
    float* cb = cbuf[w];
    int e_of = lane >> 3, p = lane & 7;

    float dpx = 0.f, dpy = 0.f;
    v2f ac0 = {0.f, 0.f}, ac1 = {0.f, 0.f};

#define GAT_LOAD(V, CB) do {                                                    \
        int lim_ = nchunk - 1;                                                  \
        _Pragma("unroll")                                                       \
        for (int e = 0; e < 8; e++) {                                           \
            int ee_ = (CB) + e;                                                 \
            int sv_ = __builtin_amdgcn_readlane(idx, (ee_ < nchunk) ? ee_ : lim_); \
            V[e] = xlh[(size_t)sv_ * 64 + lane];                                \
        }                                                                       \
    } while (0)

#define GAT_PROC(V, CB) do {                                                    \
        int rem_ = nchunk - (CB);                                               \
        v2f vf8[8];                                                             \
        _Pragma("unroll")                                                       \
        for (int e = 0; e < 8; e++) {                                           \
            float2 vf_ = __half22float2(V[e]);                                  \
            v2f vl2 = {vf_.x, vf_.y};                                           \
            vf8[e] = vl2;                                                       \
            v2f z = vl2 + vr2;                                                  \
            v2f t = __builtin_elementwise_max(z, z * NEG_SLOPE) * att2;         \
            *(v2f*)&cb[e * 132 + 2 * lane] = t;                                 \
        }                                                                       \
        lds_fence();                                                            \
        v2f s2 = {0.f, 0.f};                                                    \
        {                                                                       \
            const float4* row_ = (const float4*)&cb[e_of * 132 + p * 16];       \
            _Pragma("unroll")                                                   \
            for (int j = 0; j < 4; j++) {                                       \
                float4 f = row_[j];                                             \
                s2 += (v2f){f.x, f.y};                                          \
                s2 += (v2f){f.z, f.w};                                          \
            }                                                                   \
        }                                                                       \
        lds_fence();                                                            \
        _Pragma("unroll")                                                       \
        for (int off = 1; off <= 4; off <<= 1) {                                \
            v2f o_;                                                             \
            o_.x = __shfl_xor(s2.x, off, 64);                                   \
            o_.y = __shfl_xor(s2.y, off, 64);                                   \
            s2 += o_;                                                           \
        }                                                                       \
        float sx = s2.x, sy = s2.y;                                             \
        if (e_of >= rem_) { sx = -INFINITY; sy = -INFINITY; }                   \
        float wx = __expf(sx), wy = __expf(sy);                                 \
        dpx += wx; dpy += wy;                                                   \
        _Pragma("unroll")                                                       \
        for (int e = 0; e < 8; e++) {                                           \
            float swx = __int_as_float(__builtin_amdgcn_readlane(__float_as_int(wx), 8 * e)); \
            float swy = __int_as_float(__builtin_amdgcn_readlane(__float_as_int(wy), 8 * e)); \
            v2f w2 = {swx, swy};                                                \
            if (e & 1) ac1 = __builtin_elementwise_fma(w2, vf8[e], ac1);        \
            else       ac0 = __builtin_elementwise_fma(w2, vf8[e], ac0);        \
        }                                                                       \
    } while (0)

    for (int base = r0; base < r1; base += 64) {
        int a = base + lane;
        int idx = (int)src_sorted[(a < r1) ? a : (r1 - 1)];
        int nchunk = min(64, r1 - base);
        __half2 va[8], vb[8];
        GAT_LOAD(va, 0);
        int cb_i = 0;
        for (;;) {
            int nx = cb_i + 8;
            if (nx < nchunk) {
                GAT_LOAD(vb, nx);
                GAT_PROC(va, cb_i);
                cb_i = nx;
            } else {
                GAT_PROC(va, cb_i);
                break;
            }
            nx = cb_i + 8;
            if (nx < nchunk) {
                GAT_LOAD(va, nx);
                GAT_PROC(vb, cb_i);
                cb_i = nx;
            } else {
                GAT_PROC(vb, cb_i);
                break;
            }
        }
    }
#undef GAT_LOAD
#undef GAT_PROC

#pragma unroll
    for (int off = 8; off <= 32; off <<= 1) {
        dpx += __shfl_xor(dpx, off, 64);
        dpy += __shfl_xor(dpy, off, 64);
    }
    v2f acc = ac0 + ac1;
    h_out[(size_t)d * 64 + lane] = (acc.x / dpx + acc.y / dpy) * 0.5f + bias[lane];
}

// ---- readout GEMM fused with per-graph segment sum (proven version) ----
__global__ void readout_kernel(const float* __restrict__ h, const float* __restrict__ W,
                               const float* __restrict__ b, const int* __restrict__ batch,
                               float* __restrict__ out) {
    __shared__ float sH[16 * 64];
    __shared__ int sB[16];
    int tid = threadIdx.x;
    int base = blockIdx.x * 16;
#pragma unroll
    for (int i = 0; i < 4; i++) {
        int idx = tid + i * 256;
        int nn = base + (idx >> 6);
        sH[idx] = (nn < N_NODES) ? h[(size_t)nn * 64 + (idx & 63)] : 0.f;
    }
    if (tid < 16) sB[tid] = (base + tid < N_NODES) ? batch[base + tid] : -1;
    __syncthreads();
    int j = tid & 127, gg = tid >> 7;
    float acc[8];
#pragma unroll
    for (int n = 0; n < 8; n++) acc[n] = b[j];
    for (int k = 0; k < 64; k++) {
        float wv = W[k * OUT_DIM + j];
#pragma unroll
        for (int n = 0; n < 8; n++) acc[n] = fmaf(sH[(gg * 8 + n) * 64 + k], wv, acc[n]);
    }
    float run = 0.f; int curb = -2;
#pragma unroll
    for (int n = 0; n < 8; n++) {
        int node = base + gg * 8 + n;
        int bb = (node < N_NODES) ? sB[gg * 8 + n] : -1;
        if (bb != curb) {
            if (curb >= 0) atomicAdd(&out[curb * OUT_DIM + j], run);
            run = 0.f; curb = bb;
        }
        if (bb >= 0) run += acc[n];
    }
    if (curb >= 0) atomicAdd(&out[curb * OUT_DIM + j], run);
}

extern "C" void kernel_launch(void* const* d_in, const int* in_sizes, int n_in,
                              void* d_out, int out_size, void* d_ws, size_t ws_size,
                              hipStream_t stream) {
    const int*   x        = (const int*)d_in[0];
    const int*   edge     = (const int*)d_in[1];
    const int*   batch    = (const int*)d_in[2];
    const float* embed    = (const float*)d_in[4];
    const float* lin_W    = (const float*)d_in[5];
    const float* lin_b    = (const float*)d_in[6];
    const float* gat_Wl   = (const float*)d_in[7];
    const float* gat_bl   = (const float*)d_in[8];
    const float* gat_Wr   = (const float*)d_in[9];
    const float* gat_br   = (const float*)d_in[10];
    const float* gat_att  = (const float*)d_in[11];
    const float* gat_bias = (const float*)d_in[12];
    const float* ro_W     = (const float*)d_in[13];
    const float* ro_b     = (const float*)d_in[14];
    float* out = (float*)d_out;

    const int* srcs = edge;
    const int* dsts = edge + E_EDGES;

    float* h    = (float*)d_ws;
    __half* xlh = (__half*)(h + (size_t)N_NODES * 64);
    __half* xrh = xlh + (size_t)N_NODES * HC;
    int2* row_se       = (int2*)(xrh + (size_t)N_NODES * HC);
    int* rcnt          = (int*)(row_se + N_NODES);                      // NCHUNK*NB
    unsigned int* ebuf = (unsigned int*)(rcnt + NCHUNK * NB);           // NB*NCHUNK*RMAX (+slack)
    unsigned short* src_sorted =
        (unsigned short*)(ebuf + (size_t)NB * NCHUNK * RMAX + 4096);    // NB*BSTRIDE

    const int T = 256;
    const int gLin = (N_NODES + 15) / 16;
    const int gGat = (N_NODES + 1) / 2;

    // D1: atomic-free edge partition (+ out zero)
    edge_partition_kernel<<<NCHUNK, T, 0, stream>>>(srcs, dsts, out, rcnt, ebuf);
    // D2: per-bucket CSR + scatter
    bucket_csr_kernel<<<NB, T, 0, stream>>>(ebuf, rcnt, row_se, src_sorted);
    // D3..D8: (lin,gat) x3
    for (int l = 0; l < L_LAYERS; l++) {
        layer_lin_kernel<<<gLin, T, 0, stream>>>(
            h, x, embed, (l == 0) ? 1 : 0,
            lin_W + (size_t)l * 64 * 64, lin_b + (size_t)l * 64,
            gat_Wl + (size_t)l * 64 * 128, gat_bl + (size_t)l * 128,
            gat_Wr + (size_t)l * 64 * 128, gat_br + (size_t)l * 128,
            xlh, xrh);
        gat_kernel<<<gGat, 128, 0, stream>>>(
            (const __half2*)xlh, (const __half2*)xrh, gat_att + (size_t)l * HC,
            row_se, src_sorted, gat_bias + (size_t)l * 64, h);
    }
    // D9: readout + segment sum
    readout_kernel<<<gLin, T, 0, stream>>>(h, ro_W, ro_b, batch, out);
}

// Round 15
// 392.002 us; speedup vs baseline: 1.5794x; 1.0321x over previous
//
#include <hip/hip_runtime.h>
#include <hip/hip_fp16.h>

#define N_NODES  50000
#define E_EDGES  800000
#define E_TOT    850000   // E + N self-loops
#define H_HEADS  2
#define C_DIM    64
#define HC       128
#define L_LAYERS 3
#define OUT_DIM  128
#define G_GRAPHS 512
#define NEG_SLOPE 0.2f
#define NB       196      // node buckets of 256 nodes
#define EPB      4096     // edges per partition block
#define BSTRIDE  4864     // fixed ebuf/src slots per bucket (mean 4352, sigma 64 -> 8-sigma margin)

typedef float v2f __attribute__((ext_vector_type(2)));

__device__ __forceinline__ void lds_fence() { asm volatile("" ::: "memory"); }

// ---- init: zero graph-output accumulator + bucket write pointers ----
__global__ void init_kernel(float* __restrict__ out, int* __restrict__ bwptr) {
    int i = blockIdx.x * 256 + threadIdx.x;
    if (i < G_GRAPHS * OUT_DIM) out[i] = 0.f;
    if (blockIdx.x == 0) bwptr[threadIdx.x] = 0;
}

// ---- partition edges into fixed-stride dst-buckets with LDS staging.
// No pre-count / no global scan needed: bucket g owns ebuf[g*BSTRIDE ...],
// bwptr[g] is a zero-based cursor. Near-full-line writes (runs of ~21). ----
__global__ void edge_partition_kernel(const int* __restrict__ srcs, const int* __restrict__ dsts,
                                      int* __restrict__ bwptr, unsigned int* __restrict__ ebuf) {
    __shared__ int hist[256];
    __shared__ int lscan[256];
    __shared__ int sExcl[256];
    __shared__ int lcnt[256];
    __shared__ int gbase[256];
    __shared__ unsigned int sval[EPB];
    __shared__ unsigned char sgid[EPB];
    int tid = threadIdx.x;
    int ebase = blockIdx.x * EPB;
    hist[tid] = 0;
    __syncthreads();
    unsigned int val[16];
    int gid[16];
#pragma unroll
    for (int i = 0; i < 16; i++) {
        int e = ebase + i * 256 + tid;
        if (e < E_TOT) {
            int s, d;
            if (e < E_EDGES) { s = srcs[e]; d = dsts[e]; }
            else             { s = d = e - E_EDGES; }
            val[i] = ((unsigned)s << 8) | (unsigned)(d & 255);
            gid[i] = d >> 8;
            atomicAdd(&hist[gid[i]], 1);
        } else gid[i] = -1;
    }
    __syncthreads();
    lscan[tid] = hist[tid];
    __syncthreads();
#pragma unroll
    for (int off = 1; off < 256; off <<= 1) {
        int t = (tid >= off) ? lscan[tid - off] : 0;
        __syncthreads();
        lscan[tid] += t;
        __syncthreads();
    }
    sExcl[tid] = lscan[tid] - hist[tid];
    lcnt[tid] = 0;
    __syncthreads();
#pragma unroll
    for (int i = 0; i < 16; i++) {
        if (gid[i] >= 0) {
            int off = atomicAdd(&lcnt[gid[i]], 1);
            int idx = sExcl[gid[i]] + off;
            sval[idx] = val[i];
            sgid[idx] = (unsigned char)gid[i];
        }
    }
    if (tid < NB) {
        int c = hist[tid];
        gbase[tid] = c ? atomicAdd(&bwptr[tid], c) : 0;
    }
    __syncthreads();
    int total = lscan[255];
    for (int idx = tid; idx < total; idx += 256) {
        int g = sgid[idx];
        ebuf[(size_t)g * BSTRIDE + gbase[g] + (idx - sExcl[g])] = sval[idx];
    }
}

// ---- per-bucket: node histogram -> per-node (start,end) row_se (int2; no
// cross-bucket scan needed with fixed stride), then in-window scatter. ----
__global__ void bucket_csr_kernel(const unsigned int* __restrict__ ebuf,
                                  const int* __restrict__ bwptr,
                                  int2* __restrict__ row_se,
                                  unsigned short* __restrict__ src_sorted) {
    __shared__ int hist[256];
    __shared__ int lcnt[256];
    __shared__ int wsum[4];
    int g = blockIdx.x, tid = threadIdx.x;
    int n0 = g << 8;
    int nodes = min(256, N_NODES - n0);
    int b0 = g * BSTRIDE;
    int cnt = bwptr[g];
    hist[tid] = 0;
    lcnt[tid] = 0;
    __syncthreads();
    for (int i = tid; i < cnt; i += 256) atomicAdd(&hist[ebuf[b0 + i] & 255], 1);
    __syncthreads();
    int c = hist[tid];
    int v = c;
    int lane = tid & 63, wid = tid >> 6;
#pragma unroll
    for (int off = 1; off < 64; off <<= 1) {
        int t = __shfl_up(v, off, 64);
        if (lane >= off) v += t;
    }
    if (lane == 63) wsum[wid] = v;
    __syncthreads();
    int woff = 0;
#pragma unroll
    for (int w = 0; w < 4; w++) if (w < wid) woff += wsum[w];
    v += woff;
    int nbase = b0 + v - c;          // slot base for node n0+tid
    if (tid < nodes) row_se[n0 + tid] = make_int2(nbase, nbase + c);
    __syncthreads();
    hist[tid] = nbase;               // reuse hist as per-node base
    __syncthreads();
    for (int i = tid; i < cnt; i += 256) {
        unsigned int e = ebuf[b0 + i];
        int dl = e & 255;
        int slot = hist[dl] + atomicAdd(&lcnt[dl], 1);
        src_sorted[slot] = (unsigned short)(e >> 8);
    }
}

// ---- fused per-layer linears: h2 = relu(in@W+b); xl = h2@Wl+bl (fp16);
// xr = h2@Wr+br (fp16). k-PAIRED inner loops: sH[node][k],sH[node][k+1] are
// LDS-adjacent, so one ds_read_b64 feeds a genuine v_pk_fma_f32. Even/odd-k
// partials summed at the end (fp32 reassociation only).
// Layer 0 fuses the embedding gather. ----
__global__ void layer_lin_kernel(const float* __restrict__ h,
                                 const int* __restrict__ xs, const float* __restrict__ etab,
                                 int use_embed,
                                 const float* __restrict__ W, const float* __restrict__ b,
                                 const float* __restrict__ Wl, const float* __restrict__ bl,
                                 const float* __restrict__ Wr, const float* __restrict__ br,
                                 __half* __restrict__ xlh, __half* __restrict__ xrh) {
    __shared__ float sH[16 * 64];
    __shared__ float sH2[16 * 64];
    int tid = threadIdx.x;
    int base = blockIdx.x * 16;
#pragma unroll
    for (int i = 0; i < 4; i++) {
        int idx = tid + i * 256;
        int nn = base + (idx >> 6);
        int cc = idx & 63;
        float hv = 0.f;
        if (nn < N_NODES)
            hv = use_embed ? etab[xs[nn] * 64 + cc] : h[(size_t)nn * 64 + cc];
        sH[idx] = hv;
    }
    __syncthreads();
    {
        int c = tid & 63, g = tid >> 6;
        v2f a2[4];
#pragma unroll
        for (int n = 0; n < 4; n++) a2[n] = (v2f){b[c], 0.f};
        for (int k = 0; k < 64; k += 2) {
            v2f w2 = {W[k * 64 + c], W[(k + 1) * 64 + c]};
#pragma unroll
            for (int n = 0; n < 4; n++) {
                v2f hv2 = *(const v2f*)&sH[(g * 4 + n) * 64 + k];
                a2[n] = __builtin_elementwise_fma(hv2, w2, a2[n]);
            }
        }
#pragma unroll
        for (int n = 0; n < 4; n++)
            sH2[(g * 4 + n) * 64 + c] = fmaxf(a2[n].x + a2[n].y, 0.f);
    }
    __syncthreads();
    {
        int j = tid & 127, gg = tid >> 7;
        v2f accl2[8], accr2[8];
#pragma unroll
        for (int n = 0; n < 8; n++) {
            accl2[n] = (v2f){bl[j], 0.f};
            accr2[n] = (v2f){br[j], 0.f};
        }
        for (int k = 0; k < 64; k += 2) {
            v2f wl2 = {Wl[k * 128 + j], Wl[(k + 1) * 128 + j]};
            v2f wr2 = {Wr[k * 128 + j], Wr[(k + 1) * 128 + j]};
#pragma unroll
            for (int n = 0; n < 8; n++) {
                v2f hv2 = *(const v2f*)&sH2[(gg * 8 + n) * 64 + k];
                accl2[n] = __builtin_elementwise_fma(hv2, wl2, accl2[n]);
                accr2[n] = __builtin_elementwise_fma(hv2, wr2, accr2[n]);
            }
        }
        int hh = j >> 6, c = j & 63;
#pragma unroll
        for (int n = 0; n < 8; n++) {
            int node = base + gg * 8 + n;
            if (node < N_NODES) {
                size_t o = (size_t)node * 128 + c * 2 + hh;
                xlh[o] = __float2half(accl2[n].x + accl2[n].y);
                xrh[o] = __float2half(accr2[n].x + accr2[n].y);
            }
        }
    }
}

// ---- GATv2 edge phase (proven, 2-wave blocks): one wave per dst node,
// lane = channel, half2 = both heads. 8-edge batches, register-held fp16 vl,
// ping-pong prefetch, LDS-transpose score reduction, packed fp32 math,
// no running max, readlane weight broadcast. row_se int2 (start,end). ----
__global__ void __launch_bounds__(128)
gat_kernel(const __half2* __restrict__ xlh, const __half2* __restrict__ xrh2,
           const float* __restrict__ att, const int2* __restrict__ row_se,
           const unsigned short* __restrict__ src_sorted,
           const float* __restrict__ bias,
           float* __restrict__ h_out) {
    __shared__ __align__(16) float cbuf[2][8 * 132];
    int w = threadIdx.x >> 6;
    int d = blockIdx.x * 2 + w;
    if (d >= N_NODES) return;
    int lane = threadIdx.x & 63;
    int2 se = row_se[d];
    int r0 = se.x, r1 = se.y;
    float2 vrf = __half22float2(xrh2[(size_t)d * 64 + lane]);
    v2f vr2 = {vrf.x, vrf.y};
    v2f att2 = {att[lane], att[64 + lane]};
    float* cb = cbuf[w];
    int e_of = lane >> 3, p = lane & 7;

    float dpx = 0.f, dpy = 0.f;
    v2f ac0 = {0.f, 0.f}, ac1 = {0.f, 0.f};

#define GAT_LOAD(V, CB) do {                                                    \
        int lim_ = nchunk - 1;                                                  \
        _Pragma("unroll")                                                       \
        for (int e = 0; e < 8; e++) {                                           \
            int ee_ = (CB) + e;                                                 \
            int sv_ = __builtin_amdgcn_readlane(idx, (ee_ < nchunk) ? ee_ : lim_); \
            V[e] = xlh[(size_t)sv_ * 64 + lane];                                \
        }                                                                       \
    } while (0)

#define GAT_PROC(V, CB) do {                                                    \
        int rem_ = nchunk - (CB);                                               \
        v2f vf8[8];                                                             \
        _Pragma("unroll")                                                       \
        for (int e = 0; e < 8; e++) {                                           \
            float2 vf_ = __half22float2(V[e]);                                  \
            v2f vl2 = {vf_.x, vf_.y};                                           \
            vf8[e] = vl2;                                                       \
            v2f z = vl2 + vr2;                                                  \
            v2f t = __builtin_elementwise_max(z, z * NEG_SLOPE) * att2;         \
            *(v2f*)&cb[e * 132 + 2 * lane] = t;                                 \
        }                                                                       \
        lds_fence();                                                            \
        v2f s2 = {0.f, 0.f};                                                    \
        {                                                                       \
            const float4* row_ = (const float4*)&cb[e_of * 132 + p * 16];       \
            _Pragma("unroll")                                                   \
            for (int j = 0; j < 4; j++) {                                       \
                float4 f = row_[j];                                             \
                s2 += (v2f){f.x, f.y};                                          \
                s2 += (v2f){f.z, f.w};                                          \
            }                                                                   \
        }                                                                       \
        lds_fence();                                                            \
        _Pragma("unroll")                                                       \
        for (int off = 1; off <= 4; off <<= 1) {                                \
            v2f o_;                                                             \
            o_.x = __shfl_xor(s2.x, off, 64);                                   \
            o_.y = __shfl_xor(s2.y, off, 64);                                   \
            s2 += o_;                                                           \
        }                                                                       \
        float sx = s2.x, sy = s2.y;                                             \
        if (e_of >= rem_) { sx = -INFINITY; sy = -INFINITY; }                   \
        float wx = __expf(sx), wy = __expf(sy);                                 \
        dpx += wx; dpy += wy;                                                   \
        _Pragma("unroll")                                                       \
        for (int e = 0; e < 8; e++) {                                           \
            float swx = __int_as_float(__builtin_amdgcn_readlane(__float_as_int(wx), 8 * e)); \
            float swy = __int_as_float(__builtin_amdgcn_readlane(__float_as_int(wy), 8 * e)); \
            v2f w2 = {swx, swy};                                                \
            if (e & 1) ac1 = __builtin_elementwise_fma(w2, vf8[e], ac1);        \
            else       ac0 = __builtin_elementwise_fma(w2, vf8[e], ac0);        \
        }                                                                       \
    } while (0)

    for (int base = r0; base < r1; base += 64) {
        int a = base + lane;
        int idx = (int)src_sorted[(a < r1) ? a : (r1 - 1)];
        int nchunk = min(64, r1 - base);
        __half2 va[8], vb[8];
        GAT_LOAD(va, 0);
        int cb_i = 0;
        for (;;) {
            int nx = cb_i + 8;
            if (nx < nchunk) {
                GAT_LOAD(vb, nx);
                GAT_PROC(va, cb_i);
                cb_i = nx;
            } else {
                GAT_PROC(va, cb_i);
                break;
            }
            nx = cb_i + 8;
            if (nx < nchunk) {
                GAT_LOAD(va, nx);
                GAT_PROC(vb, cb_i);
                cb_i = nx;
            } else {
                GAT_PROC(vb, cb_i);
                break;
            }
        }
    }
#undef GAT_LOAD
#undef GAT_PROC

    // cross-group reduce: each 8-lane group holds its own dp partial (uniform
    // within group); xor over offs 8/16/32 sums the 8 groups exactly once.
#pragma unroll
    for (int off = 8; off <= 32; off <<= 1) {
        dpx += __shfl_xor(dpx, off, 64);
        dpy += __shfl_xor(dpy, off, 64);
    }
    v2f acc = ac0 + ac1;
    h_out[(size_t)d * 64 + lane] = (acc.x / dpx + acc.y / dpy) * 0.5f + bias[lane];
}

// ---- readout GEMM fused with per-graph segment sum (proven version:
// node-major LDS broadcasts, scalar FMA, batch-sorted run grouping) ----
__global__ void readout_kernel(const float* __restrict__ h, const float* __restrict__ W,
                               const float* __restrict__ b, const int* __restrict__ batch,
                               float* __restrict__ out) {
    __shared__ float sH[16 * 64];
    __shared__ int sB[16];
    int tid = threadIdx.x;
    int base = blockIdx.x * 16;
#pragma unroll
    for (int i = 0; i < 4; i++) {
        int idx = tid + i * 256;
        int nn = base + (idx >> 6);
        sH[idx] = (nn < N_NODES) ? h[(size_t)nn * 64 + (idx & 63)] : 0.f;
    }
    if (tid < 16) sB[tid] = (base + tid < N_NODES) ? batch[base + tid] : -1;
    __syncthreads();
    int j = tid & 127, gg = tid >> 7;
    float acc[8];
#pragma unroll
    for (int n = 0; n < 8; n++) acc[n] = b[j];
    for (int k = 0; k < 64; k++) {
        float wv = W[k * OUT_DIM + j];
#pragma unroll
        for (int n = 0; n < 8; n++) acc[n] = fmaf(sH[(gg * 8 + n) * 64 + k], wv, acc[n]);
    }
    float run = 0.f; int curb = -2;
#pragma unroll
    for (int n = 0; n < 8; n++) {
        int node = base + gg * 8 + n;
        int bb = (node < N_NODES) ? sB[gg * 8 + n] : -1;
        if (bb != curb) {
            if (curb >= 0) atomicAdd(&out[curb * OUT_DIM + j], run);
            run = 0.f; curb = bb;
        }
        if (bb >= 0) run += acc[n];
    }
    if (curb >= 0) atomicAdd(&out[curb * OUT_DIM + j], run);
}

extern "C" void kernel_launch(void* const* d_in, const int* in_sizes, int n_in,
                              void* d_out, int out_size, void* d_ws, size_t ws_size,
                              hipStream_t stream) {
    const int*   x        = (const int*)d_in[0];
    const int*   edge     = (const int*)d_in[1];
    const int*   batch    = (const int*)d_in[2];
    const float* embed    = (const float*)d_in[4];
    const float* lin_W    = (const float*)d_in[5];
    const float* lin_b    = (const float*)d_in[6];
    const float* gat_Wl   = (const float*)d_in[7];
    const float* gat_bl   = (const float*)d_in[8];
    const float* gat_Wr   = (const float*)d_in[9];
    const float* gat_br   = (const float*)d_in[10];
    const float* gat_att  = (const float*)d_in[11];
    const float* gat_bias = (const float*)d_in[12];
    const float* ro_W     = (const float*)d_in[13];
    const float* ro_b     = (const float*)d_in[14];
    float* out = (float*)d_out;

    const int* srcs = edge;
    const int* dsts = edge + E_EDGES;

    float* h    = (float*)d_ws;
    __half* xlh = (__half*)(h + (size_t)N_NODES * 64);
    __half* xrh = xlh + (size_t)N_NODES * HC;
    int2* row_se       = (int2*)(xrh + (size_t)N_NODES * HC);
    int* bwptr         = (int*)(row_se + N_NODES);
    unsigned int* ebuf = (unsigned int*)(bwptr + 256);
    unsigned short* src_sorted = (unsigned short*)(ebuf + (size_t)NB * BSTRIDE);

    const int T = 256;
    const int gInit = (G_GRAPHS * OUT_DIM + 255) / 256;
    const int gPart = (E_TOT + EPB - 1) / EPB;
    const int gLin  = (N_NODES + 15) / 16;
    const int gGat  = (N_NODES + 1) / 2;

    init_kernel<<<gInit, T, 0, stream>>>(out, bwptr);
    edge_partition_kernel<<<gPart, T, 0, stream>>>(srcs, dsts, bwptr, ebuf);
    bucket_csr_kernel<<<NB, T, 0, stream>>>(ebuf, bwptr, row_se, src_sorted);

    for (int l = 0; l < L_LAYERS; l++) {
        layer_lin_kernel<<<gLin, T, 0, stream>>>(
            h, x, embed, (l == 0) ? 1 : 0,
            lin_W + (size_t)l * 64 * 64, lin_b + (size_t)l * 64,
            gat_Wl + (size_t)l * 64 * 128, gat_bl + (size_t)l * 128,
            gat_Wr + (size_t)l * 64 * 128, gat_br + (size_t)l * 128,
            xlh, xrh);
        gat_kernel<<<gGat, 128, 0, stream>>>(
            (const __half2*)xlh, (const __half2*)xrh, gat_att + (size_t)l * HC,
            row_se, src_sorted, gat_bias + (size_t)l * 64, h);
    }

    readout_kernel<<<gLin, T, 0, stream>>>(h, ro_W, ro_b, batch, out);
}